// Round 15
// baseline (1381.046 us; speedup 1.0000x reference)
//
#include <hip/hip_runtime.h>
#include <math.h>

// Problem dims
#define Sn 128
#define Bn 16
#define Hn 1024
#define En 512
#define Vn 32000
#define H3 3072
#define NL0 32
#define NL1 64

typedef _Float16 h16;
typedef __attribute__((ext_vector_type(4))) _Float16 h16x4;
typedef __attribute__((ext_vector_type(8))) _Float16 h16x8;
typedef __attribute__((ext_vector_type(4))) float f32x4;

// ---------- fused f32 -> fp16 convert for ALL operands (one launch) ----------
#define Q_EMB   4096000
#define Q_WIH0  (Q_EMB + 393216)
#define Q_W1    (Q_WIH0 + 262144)
#define Q_W2    (Q_W1 + 131072)
#define Q_WHH0  (Q_W2 + 786432)
#define Q_WIH1  (Q_WHH0 + 786432)
#define Q_WHH1  (Q_WIH1 + 786432)
#define Q_HID   (Q_WHH1 + 8192)
__global__ __launch_bounds__(256) void cvt_all_k(
    const float* __restrict__ emb, const float* __restrict__ wih0,
    const float* __restrict__ w1, const float* __restrict__ w2,
    const float* __restrict__ whh0, const float* __restrict__ wih1,
    const float* __restrict__ whh1, const float* __restrict__ hid,
    h16* __restrict__ E, h16* __restrict__ A, h16* __restrict__ B1,
    h16* __restrict__ B2, h16* __restrict__ D0, h16* __restrict__ D1,
    h16* __restrict__ D2, h16* __restrict__ HD)
{
  int i = blockIdx.x * 256 + threadIdx.x;
  const float* s; h16* d; int o;
  if      (i < Q_EMB)  { s = emb;  d = E;  o = i; }
  else if (i < Q_WIH0) { s = wih0; d = A;  o = i - Q_EMB; }
  else if (i < Q_W1)   { s = w1;   d = B1; o = i - Q_WIH0; }
  else if (i < Q_W2)   { s = w2;   d = B2; o = i - Q_W1; }
  else if (i < Q_WHH0) { s = whh0; d = D0; o = i - Q_W2; }
  else if (i < Q_WIH1) { s = wih1; d = D1; o = i - Q_WHH0; }
  else if (i < Q_WHH1) { s = whh1; d = D2; o = i - Q_WIH1; }
  else                 { s = hid;  d = HD; o = i - Q_WHH1; }
  float4 v = *(const float4*)(s + (size_t)o * 4);
  h16x4 ov = { (h16)v.x, (h16)v.y, (h16)v.z, (h16)v.w };
  *(h16x4*)(d + (size_t)o * 4) = ov;
}

// ---------- embedding gather -> fp16 X, time-major rows t = s*Bn + b ----------
__global__ void embed_k(const int* __restrict__ trg, const float* __restrict__ emb,
                        h16* __restrict__ Xh) {
  int t = blockIdx.x;
  int s = t >> 4, b = t & 15;
  int tok = trg[b * Sn + s];
  const float* src = emb + (size_t)tok * En;
  int e = threadIdx.x * 4;
  float4 v = *(const float4*)(src + e);
  h16x4 o = { (h16)v.x, (h16)v.y, (h16)v.z, (h16)v.w };
  *(h16x4*)(Xh + (size_t)t * En + e) = o;
}

// ---------- fp16 MFMA GEMM 128x128 (for GI0 only) ----------
template<int OUT_MODE, bool RELU, bool SWZ>
__global__ __launch_bounds__(256) void gemm_bt(
    const h16* __restrict__ A, const h16* __restrict__ B,
    const float* __restrict__ bias, void* __restrict__ C,
    int M, int N, int K)
{
  __shared__ h16 As[128 * 64];
  __shared__ h16 Bs[128 * 64];
  int tid = threadIdx.x;
  int l = tid & 63, wv = tid >> 6;
  int wr = wv >> 1, wc = wv & 1;

  int work = blockIdx.x;
  if (SWZ) { int q = gridDim.x >> 3; work = (work & 7) * q + (work >> 3); }
  int nMp = M >> 7;
  int brow = (work % nMp) << 7;
  int bcol = (work / nMp) << 7;

  f32x4 acc[4][4];
#pragma unroll
  for (int m = 0; m < 4; ++m)
#pragma unroll
    for (int n = 0; n < 4; ++n) acc[m][n] = (f32x4){0.f, 0.f, 0.f, 0.f};

  int nkt = K >> 6;
  for (int kt = 0; kt < nkt; ++kt) {
    const h16* Ag = A + (size_t)brow * K + kt * 64;
    const h16* Bg = B + (size_t)bcol * K + kt * 64;
#pragma unroll
    for (int c = tid; c < 2048; c += 256) {
      int half = c >> 10;
      int cc = c & 1023;
      int row = cc >> 3, slot = cc & 7;
      const h16* src = (half ? Bg : Ag) + (size_t)row * K + slot * 8;
      uint4 v = *(const uint4*)src;
      h16* dst = (half ? Bs : As) + row * 64 + ((slot ^ (row & 7)) << 3);
      *(uint4*)dst = v;
    }
    __syncthreads();
#pragma unroll
    for (int kk = 0; kk < 2; ++kk) {
      h16x8 af[4], bfr[4];
      int rb = wr * 64 + (l & 15);
      int cb2 = wc * 64 + (l & 15);
      int slot = kk * 4 + (l >> 4);
#pragma unroll
      for (int m = 0; m < 4; ++m) {
        int r = rb + m * 16;
        af[m] = *(const h16x8*)&As[r * 64 + ((slot ^ (r & 7)) << 3)];
      }
#pragma unroll
      for (int n = 0; n < 4; ++n) {
        int r = cb2 + n * 16;
        bfr[n] = *(const h16x8*)&Bs[r * 64 + ((slot ^ (r & 7)) << 3)];
      }
#pragma unroll
      for (int m = 0; m < 4; ++m)
#pragma unroll
        for (int n = 0; n < 4; ++n)
          acc[m][n] = __builtin_amdgcn_mfma_f32_16x16x32_f16(af[m], bfr[n], acc[m][n], 0, 0, 0);
    }
    __syncthreads();
  }

#pragma unroll
  for (int m = 0; m < 4; ++m) {
    int row0 = brow + wr * 64 + m * 16 + ((l >> 4) << 2);
#pragma unroll
    for (int n = 0; n < 4; ++n) {
      int col = bcol + wc * 64 + n * 16 + (l & 15);
      float bv = bias ? bias[col] : 0.f;
#pragma unroll
      for (int i = 0; i < 4; ++i) {
        int row = row0 + i;
        float v = acc[m][n][i] + bv;
        if (RELU) v = fmaxf(v, 0.f);
        if (OUT_MODE == 1) {
          ((h16*)C)[(size_t)row * N + col] = (h16)v;
        } else {
          ((float*)C)[(size_t)row * N + col] = v;
        }
      }
    }
  }
}

// ================= mega kernel: gru dataflow + progressive head =================

__device__ __forceinline__ void wait_fL1(int* fL1, int target, int tid) {
  if (tid < 64) {
    for (;;) {
      int v = __hip_atomic_load(&fL1[tid << 5], __ATOMIC_RELAXED, __HIP_MEMORY_SCOPE_AGENT);
      if (__all(v >= target)) break;
      __builtin_amdgcn_s_sleep(8);
    }
  }
  __syncthreads();
  asm volatile("" ::: "memory");
}

__device__ __forceinline__ void wait_cnt(int* c, int target, int tid) {
  if (tid == 0) {
    while (__hip_atomic_load(c, __ATOMIC_RELAXED, __HIP_MEMORY_SCOPE_AGENT) < target)
      __builtin_amdgcn_s_sleep(8);
  }
  __syncthreads();
  asm volatile("" ::: "memory");
}

__device__ __forceinline__ void publish_cnt(int* c) {
  __syncthreads();                   // drains each wave's vmem before barrier
  if (threadIdx.x == 0) {
    __threadfence();                 // push block's stores to the coherence point
    atomicAdd(c, 1);
  }
}

// 128x128 head GEMM, 384 threads (waves 4,5 stage-only), C = h16 row-major
__device__ __forceinline__ void gemm_head128(
    const h16* __restrict__ A, const h16* __restrict__ B, const float* __restrict__ bias,
    h16* __restrict__ C, int ldc, int K, int relu, char* dyn, int tid)
{
  h16* As = (h16*)dyn;
  h16* Bs = (h16*)(dyn + 16384);
  int l = tid & 63, wv = tid >> 6;
  int wr = wv >> 1, wc = wv & 1;
  f32x4 acc[4][4];
#pragma unroll
  for (int m = 0; m < 4; ++m)
#pragma unroll
    for (int n = 0; n < 4; ++n) acc[m][n] = (f32x4){0.f, 0.f, 0.f, 0.f};
  int nkt = K >> 6;
  for (int kt = 0; kt < nkt; ++kt) {
    const h16* Ag = A + kt * 64;
    const h16* Bg = B + kt * 64;
    for (int c = tid; c < 2048; c += 384) {
      int half = c >> 10, cc = c & 1023, row = cc >> 3, slot = cc & 7;
      const h16* src = (half ? Bg : Ag) + (size_t)row * K + slot * 8;
      uint4 v = *(const uint4*)src;
      h16* dst = (half ? Bs : As) + row * 64 + ((slot ^ (row & 7)) << 3);
      *(uint4*)dst = v;
    }
    __syncthreads();
    if (wv < 4) {
#pragma unroll
      for (int kk = 0; kk < 2; ++kk) {
        h16x8 af[4], bfr[4];
        int rb = wr * 64 + (l & 15);
        int cb2 = wc * 64 + (l & 15);
        int slot = kk * 4 + (l >> 4);
#pragma unroll
        for (int m = 0; m < 4; ++m) {
          int r = rb + m * 16;
          af[m] = *(const h16x8*)&As[r * 64 + ((slot ^ (r & 7)) << 3)];
        }
#pragma unroll
        for (int n = 0; n < 4; ++n) {
          int r = cb2 + n * 16;
          bfr[n] = *(const h16x8*)&Bs[r * 64 + ((slot ^ (r & 7)) << 3)];
        }
#pragma unroll
        for (int m = 0; m < 4; ++m)
#pragma unroll
          for (int n = 0; n < 4; ++n)
            acc[m][n] = __builtin_amdgcn_mfma_f32_16x16x32_f16(af[m], bfr[n], acc[m][n], 0, 0, 0);
      }
    }
    __syncthreads();
  }
  if (wv < 4) {
#pragma unroll
    for (int m = 0; m < 4; ++m) {
      int row0 = wr * 64 + m * 16 + ((l >> 4) << 2);
#pragma unroll
      for (int n = 0; n < 4; ++n) {
        int col = wc * 64 + n * 16 + (l & 15);
        float bv = bias[col];
#pragma unroll
        for (int i = 0; i < 4; ++i) {
          float v = acc[m][n][i] + bv;
          if (relu) v = fmaxf(v, 0.f);
          C[(size_t)(row0 + i) * ldc + col] = (h16)v;
        }
      }
    }
  }
}

// 128x256 logit GEMM, 384 threads; writes f32 with (b*128+s) row remap
__device__ __forceinline__ void gemm_headlogit(
    const h16* __restrict__ A, const h16* __restrict__ B, const float* __restrict__ bias,
    float* __restrict__ C, int growbase, char* dyn, int tid)
{
  h16* As = (h16*)dyn;                 // 128*64
  h16* Bs = (h16*)(dyn + 16384);       // 256*64
  int l = tid & 63, wv = tid >> 6;
  int wr = wv >> 1, wc = wv & 1;
  f32x4 acc[4][8];
#pragma unroll
  for (int m = 0; m < 4; ++m)
#pragma unroll
    for (int n = 0; n < 8; ++n) acc[m][n] = (f32x4){0.f, 0.f, 0.f, 0.f};
  for (int kt = 0; kt < 8; ++kt) {
    const h16* Ag = A + kt * 64;
    const h16* Bg = B + kt * 64;
    for (int c = tid; c < 3072; c += 384) {
      int isB = (c >= 1024);
      int cc = isB ? (c - 1024) : c;
      int row = cc >> 3, slot = cc & 7;
      const h16* src = (isB ? Bg : Ag) + (size_t)row * 512 + slot * 8;
      uint4 v = *(const uint4*)src;
      h16* dst = (isB ? Bs : As) + row * 64 + ((slot ^ (row & 7)) << 3);
      *(uint4*)dst = v;
    }
    __syncthreads();
    if (wv < 4) {
#pragma unroll
      for (int kk = 0; kk < 2; ++kk) {
        h16x8 af[4], bfr[8];
        int rb = wr * 64 + (l & 15);
        int cb2 = wc * 128 + (l & 15);
        int slot = kk * 4 + (l >> 4);
#pragma unroll
        for (int m = 0; m < 4; ++m) {
          int r = rb + m * 16;
          af[m] = *(const h16x8*)&As[r * 64 + ((slot ^ (r & 7)) << 3)];
        }
#pragma unroll
        for (int n = 0; n < 8; ++n) {
          int r = cb2 + n * 16;
          bfr[n] = *(const h16x8*)&Bs[r * 64 + ((slot ^ (r & 7)) << 3)];
        }
#pragma unroll
        for (int m = 0; m < 4; ++m)
#pragma unroll
          for (int n = 0; n < 8; ++n)
            acc[m][n] = __builtin_amdgcn_mfma_f32_16x16x32_f16(af[m], bfr[n], acc[m][n], 0, 0, 0);
      }
    }
    __syncthreads();
  }
  if (wv < 4) {
#pragma unroll
    for (int m = 0; m < 4; ++m) {
      int row0 = wr * 64 + m * 16 + ((l >> 4) << 2);
#pragma unroll
      for (int n = 0; n < 8; ++n) {
        int col = wc * 128 + n * 16 + (l & 15);
        float bv = bias[col];
#pragma unroll
        for (int i = 0; i < 4; ++i) {
          int grow = growbase + row0 + i;
          int rr = ((grow & 15) << 7) + (grow >> 4);   // b*128 + s
          C[(size_t)rr * Vn + col] = acc[m][n][i] + bv;
        }
      }
    }
  }
}

__global__ __launch_bounds__(384) void mega(
    const float* __restrict__ gi0,
    const float* __restrict__ hidden,
    const h16* __restrict__ hinit16,
    const h16* __restrict__ whh0, const float* __restrict__ bhh0,
    const h16* __restrict__ wih1, const float* __restrict__ bih1,
    const h16* __restrict__ whh1, const float* __restrict__ bhh1,
    h16* __restrict__ h0ring, h16* __restrict__ H1A,
    int* __restrict__ flags,
    const h16* __restrict__ w1H, const float* __restrict__ b1, h16* __restrict__ Tb,
    const h16* __restrict__ w2H, const float* __restrict__ b2, h16* __restrict__ Ub,
    const h16* __restrict__ embH, const float* __restrict__ b_gen,
    float* __restrict__ out)
{
  extern __shared__ char dyn[];
  int bid = blockIdx.x;
  int tid = threadIdx.x;

  __threadfence();                   // replay-staleness guard (inv local caches)

  int* fL0  = flags;                 // 32 flags @ stride 32 ints
  int* fL1  = flags + 1024;          // 64 flags @ stride 32 ints
  int* cnt1 = flags + 3072;          // 16 counters @ stride 8 ints
  int* cnt2 = flags + 3328;          // 16 counters @ stride 8 ints

  if (bid < NL0 + NL1) {
    // ---------------- gru dataflow (round-8 verbatim, exclusive CU via big LDS) ----------------
    __builtin_amdgcn_s_setprio(1);
    float* exch = (float*)dyn;       // 5 x 256 floats
    int w = tid >> 6, l = tid & 63;
    int li = l & 15;
    int ko = (l >> 4) << 3;
    int b0 = (l >> 4) << 2;

    if (bid < NL0) {
      int gate = w >> 1, ch = w & 1;
      int j = bid * 32 + ch * 16 + li;
      h16x8 Bf[32];
      {
        const h16* wp = whh0 + ((size_t)((gate << 10) + j) << 10) + ko;
#pragma unroll
        for (int t = 0; t < 32; ++t) Bf[t] = *(const h16x8*)(wp + t * 32);
      }
      float bR = 0.f, bZ = 0.f, bN = 0.f;
      float hprev[4];
      if (gate == 2) {
        bR = bhh0[j]; bZ = bhh0[1024 + j]; bN = bhh0[2048 + j];
#pragma unroll
        for (int i = 0; i < 4; ++i) hprev[i] = hidden[((b0 + i) << 10) + j];
      }
      for (int s = 0; s < Sn; ++s) {
        if (s > 0) {
          if (w == 0 && l < NL0)
            while (__hip_atomic_load(&fL0[l << 5], __ATOMIC_RELAXED, __HIP_MEMORY_SCOPE_AGENT) < s) {}
          __syncthreads();
          asm volatile("" ::: "memory");
        }
        float gr[4], gz[4], gn[4];
        if (gate == 2) {
          const float* gb = gi0 + ((size_t)s << 4) * H3;
#pragma unroll
          for (int i = 0; i < 4; ++i) {
            const float* g = gb + (size_t)(b0 + i) * H3 + j;
            gr[i] = g[0]; gz[i] = g[1024]; gn[i] = g[2048];
          }
        }
        const h16* hsrc = (s == 0) ? hinit16 : h0ring + (((size_t)(s - 1)) << 14);
        const h16* Ap = hsrc + (li << 10) + ko;
        f32x4 acc = (f32x4){0.f, 0.f, 0.f, 0.f};
#pragma unroll
        for (int t = 0; t < 32; ++t)
          acc = __builtin_amdgcn_mfma_f32_16x16x32_f16(*(const h16x8*)(Ap + t * 32), Bf[t], acc, 0, 0, 0);
        if (w < 4) {
#pragma unroll
          for (int i = 0; i < 4; ++i) exch[w * 256 + ((b0 + i) << 4) + li] = acc[i];
        }
        __syncthreads();
        if (gate == 2) {
#pragma unroll
          for (int i = 0; i < 4; ++i) {
            int e = ((b0 + i) << 4) + li;
            float r = 1.f / (1.f + expf(-(exch[ch * 256 + e] + bR + gr[i])));
            float z = 1.f / (1.f + expf(-(exch[(2 + ch) * 256 + e] + bZ + gz[i])));
            float n = tanhf(gn[i] + r * (acc[i] + bN));
            float o = (1.f - z) * n + z * hprev[i];
            hprev[i] = o;
            h16 hv = (h16)o; unsigned short us; __builtin_memcpy(&us, &hv, 2);
            __hip_atomic_store((unsigned short*)h0ring + (((size_t)s) << 14) + ((b0 + i) << 10) + j,
                               us, __ATOMIC_RELAXED, __HIP_MEMORY_SCOPE_AGENT);
          }
        }
        __syncthreads();
        if (tid == 0)
          __hip_atomic_store(&fL0[bid << 5], s + 1, __ATOMIC_RELAXED, __HIP_MEMORY_SCOPE_AGENT);
      }
    } else {
      int bl = bid - NL0;
      int j = (bl << 4) + li;
      int isHH = (w >= 3);
      int gate = isHH ? (w - 3) : w;
      h16x8 Bf[32];
      {
        const h16* wsrc = isHH ? whh1 : wih1;
        const h16* wp = wsrc + ((size_t)((gate << 10) + j) << 10) + ko;
#pragma unroll
        for (int t = 0; t < 32; ++t) Bf[t] = *(const h16x8*)(wp + t * 32);
      }
      float bIR = 0.f, bIZ = 0.f, bIN = 0.f, bHR = 0.f, bHZ = 0.f, bHN = 0.f;
      float hprev[4];
      if (w == 5) {
        bIR = bih1[j]; bIZ = bih1[1024 + j]; bIN = bih1[2048 + j];
        bHR = bhh1[j]; bHZ = bhh1[1024 + j]; bHN = bhh1[2048 + j];
#pragma unroll
        for (int i = 0; i < 4; ++i) hprev[i] = hidden[16384 + ((b0 + i) << 10) + j];
      }
      for (int s = 1; s <= Sn; ++s) {
        if (w == 0) {
          if (l < NL0)
            while (__hip_atomic_load(&fL0[l << 5], __ATOMIC_RELAXED, __HIP_MEMORY_SCOPE_AGENT) < s) {}
        } else if (w == 1 && s >= 2) {
          while (__hip_atomic_load(&fL1[l << 5], __ATOMIC_RELAXED, __HIP_MEMORY_SCOPE_AGENT) < s) {}
        }
        __syncthreads();
        asm volatile("" ::: "memory");
        const h16* hsrc = isHH
            ? ((s == 1) ? hinit16 + 16384 : H1A + (((size_t)(s - 2)) << 14))
            : (h0ring + (((size_t)(s - 1)) << 14));
        const h16* Ap = hsrc + (li << 10) + ko;
        f32x4 acc = (f32x4){0.f, 0.f, 0.f, 0.f};
#pragma unroll
        for (int t = 0; t < 32; ++t)
          acc = __builtin_amdgcn_mfma_f32_16x16x32_f16(*(const h16x8*)(Ap + t * 32), Bf[t], acc, 0, 0, 0);
        if (w < 5) {
#pragma unroll
          for (int i = 0; i < 4; ++i) exch[w * 256 + ((b0 + i) << 4) + li] = acc[i];
        }
        __syncthreads();
        if (w == 5) {
#pragma unroll
          for (int i = 0; i < 4; ++i) {
            int e = ((b0 + i) << 4) + li;
            float r = 1.f / (1.f + expf(-(exch[e] + bIR + exch[768 + e] + bHR)));
            float z = 1.f / (1.f + expf(-(exch[256 + e] + bIZ + exch[1024 + e] + bHZ)));
            float n = tanhf(exch[512 + e] + bIN + r * (acc[i] + bHN));
            float o = (1.f - z) * n + z * hprev[i];
            hprev[i] = o;
            h16 hv = (h16)o; unsigned short us; __builtin_memcpy(&us, &hv, 2);
            __hip_atomic_store((unsigned short*)H1A + (((size_t)(s - 1)) << 14) + ((b0 + i) << 10) + j,
                               us, __ATOMIC_RELAXED, __HIP_MEMORY_SCOPE_AGENT);
          }
        }
        __syncthreads();
        if (tid == 0)
          __hip_atomic_store(&fL1[bl << 5], s + 1, __ATOMIC_RELAXED, __HIP_MEMORY_SCOPE_AGENT);
      }
    }
    return;
  }

  // ---------------- progressive head ----------------
  int hb = bid - (NL0 + NL1);
  int m = hb / 137;
  int r = hb - m * 137;

  if (r < 8) {
    // MLP1: Tb[128m.., 128r..] = relu(H1A_panel @ w1^T + b1)
    wait_fL1(fL1, 8 * m + 9, tid);
    gemm_head128(H1A + (size_t)(m * 128) * Hn, w1H + (size_t)(r * 128) * Hn,
                 b1 + r * 128, Tb + (size_t)(m * 128) * Hn + r * 128, Hn, Hn, 1, dyn, tid);
    publish_cnt(&cnt1[m << 3]);
  } else if (r < 12) {
    // MLP2: Ub[128m.., 128(r-8)..] = Tb_panel @ w2^T + b2
    int rn = r - 8;
    wait_cnt(&cnt1[m << 3], 8, tid);
    gemm_head128(Tb + (size_t)(m * 128) * Hn, w2H + (size_t)(rn * 128) * Hn,
                 b2 + rn * 128, Ub + (size_t)(m * 128) * En + rn * 128, En, Hn, 0, dyn, tid);
    publish_cnt(&cnt2[m << 3]);
  } else {
    // logit: out rows panel m, cols [256*(r-12) ..)
    int np = r - 12;
    wait_cnt(&cnt2[m << 3], 4, tid);
    gemm_headlogit(Ub + (size_t)(m * 128) * En, embH + (size_t)(np * 256) * En,
                   b_gen + np * 256, out + np * 256, m * 128, dyn, tid);
  }
}

extern "C" void kernel_launch(void* const* d_in, const int* in_sizes, int n_in,
                              void* d_out, int out_size, void* d_ws, size_t ws_size,
                              hipStream_t stream) {
  const float* hidden = (const float*)d_in[0];
  const int*   trg    = (const int*)d_in[1];
  const float* emb    = (const float*)d_in[2];
  const float* w_ih0  = (const float*)d_in[3];
  const float* w_hh0  = (const float*)d_in[4];
  const float* b_ih0  = (const float*)d_in[5];
  const float* b_hh0  = (const float*)d_in[6];
  const float* w_ih1  = (const float*)d_in[7];
  const float* w_hh1  = (const float*)d_in[8];
  const float* b_ih1  = (const float*)d_in[9];
  const float* b_hh1  = (const float*)d_in[10];
  const float* w1     = (const float*)d_in[11];
  const float* b1     = (const float*)d_in[12];
  const float* w2     = (const float*)d_in[13];
  const float* b2     = (const float*)d_in[14];
  const float* b_gen  = (const float*)d_in[15];

  char* ws = (char*)d_ws;
  size_t off = 0;
  float* GI0    = (float*)(ws + off); off += (size_t)Sn * Bn * H3 * 4;      // 25.2 MB
  h16* Xh       = (h16*)(ws + off);   off += (size_t)Sn * Bn * En * 2;
  h16* embH     = (h16*)(ws + off);   off += (size_t)Vn * En * 2;
  h16* wih0H    = (h16*)(ws + off);   off += (size_t)H3 * En * 2;
  h16* w1H      = (h16*)(ws + off);   off += (size_t)Hn * Hn * 2;
  h16* w2H      = (h16*)(ws + off);   off += (size_t)En * Hn * 2;
  h16* whh0H    = (h16*)(ws + off);   off += (size_t)H3 * Hn * 2;
  h16* wih1H    = (h16*)(ws + off);   off += (size_t)H3 * Hn * 2;
  h16* whh1H    = (h16*)(ws + off);   off += (size_t)H3 * Hn * 2;
  h16* H1A      = (h16*)(ws + off);   off += (size_t)Sn * Bn * Hn * 2;      // 4.2 MB
  h16* h0ring   = (h16*)(ws + off);   off += (size_t)Sn * Bn * Hn * 2;      // 4.2 MB
  h16* hinit16  = (h16*)(ws + off);   off += (size_t)2 * Bn * Hn * 2;
  h16* Tb       = (h16*)(ws + off);   off += (size_t)Sn * Bn * Hn * 2;      // 4.2 MB
  h16* Ub       = (h16*)(ws + off);   off += (size_t)Sn * Bn * En * 2;      // 2.1 MB
  int* flags    = (int*)(ws + off);   off += 16384;

  // fp16 copies of all operands (one fused launch) + embedding gather
  cvt_all_k<<<28320, 256, 0, stream>>>(emb, w_ih0, w1, w2, w_hh0, w_ih1, w_hh1, hidden,
                                       embH, wih0H, w1H, w2H, whh0H, wih1H, whh1H, hinit16);
  embed_k<<<Sn * Bn, 128, 0, stream>>>(trg, emb, Xh);

  // GI0 = X @ w_ih0^T + b_ih0 (hoisted out of the recurrence)
  gemm_bt<0, false, true><<<384, 256, 0, stream>>>(Xh, wih0H, b_ih0, GI0, Sn * Bn, H3, En);

  // mega: 96 gru blocks (exclusive CUs via 96KB LDS) + 2192 head blocks, dataflow sync
  (void)hipMemsetAsync(flags, 0, 16384, stream);
  const int LDSZ = 98304;   // 1 block/CU: no head block shares a CU with a gru block
  (void)hipFuncSetAttribute(reinterpret_cast<const void*>(mega),
                            hipFuncAttributeMaxDynamicSharedMemorySize, LDSZ);
  mega<<<NL0 + NL1 + 16 * 137, 384, LDSZ, stream>>>(
      GI0, hidden, hinit16, whh0H, b_hh0, wih1H, b_ih1, whh1H, b_hh1,
      h0ring, H1A, flags, w1H, b1, Tb, w2H, b2, Ub, embH, b_gen, (float*)d_out);
}

// Round 16
// 1232.851 us; speedup vs baseline: 1.1202x; 1.1202x over previous
//
#include <hip/hip_runtime.h>
#include <math.h>

// Problem dims
#define Sn 128
#define Bn 16
#define Hn 1024
#define En 512
#define Vn 32000
#define H3 3072
#define NL0 32
#define NL1 64
#define NGI 384     // GI0 tiles: 16 panels x 24 col-tiles

typedef _Float16 h16;
typedef __attribute__((ext_vector_type(4))) _Float16 h16x4;
typedef __attribute__((ext_vector_type(8))) _Float16 h16x8;
typedef __attribute__((ext_vector_type(4))) float f32x4;

// ---------- fused f32 -> fp16 convert (emb, wih0, w1, w2, hidden) ----------
#define Q_EMB   4096000
#define Q_WIH0  (Q_EMB + 393216)
#define Q_W1    (Q_WIH0 + 262144)
#define Q_W2    (Q_W1 + 131072)
#define Q_HID   (Q_W2 + 8192)
__global__ __launch_bounds__(256) void cvt_all_k(
    const float* __restrict__ emb, const float* __restrict__ wih0,
    const float* __restrict__ w1, const float* __restrict__ w2,
    const float* __restrict__ hid,
    h16* __restrict__ E, h16* __restrict__ A, h16* __restrict__ B1,
    h16* __restrict__ B2, h16* __restrict__ HD)
{
  int i = blockIdx.x * 256 + threadIdx.x;
  if (i >= Q_HID) return;
  const float* s; h16* d; int o;
  if      (i < Q_EMB)  { s = emb;  d = E;  o = i; }
  else if (i < Q_WIH0) { s = wih0; d = A;  o = i - Q_EMB; }
  else if (i < Q_W1)   { s = w1;   d = B1; o = i - Q_WIH0; }
  else if (i < Q_W2)   { s = w2;   d = B2; o = i - Q_W1; }
  else                 { s = hid;  d = HD; o = i - Q_W2; }
  float4 v = *(const float4*)(s + (size_t)o * 4);
  h16x4 ov = { (h16)v.x, (h16)v.y, (h16)v.z, (h16)v.w };
  *(h16x4*)(d + (size_t)o * 4) = ov;
}

// ---------- embedding gather -> fp16 X, time-major rows t = s*Bn + b ----------
__global__ void embed_k(const int* __restrict__ trg, const float* __restrict__ emb,
                        h16* __restrict__ Xh) {
  int t = blockIdx.x;
  int s = t >> 4, b = t & 15;
  int tok = trg[b * Sn + s];
  const float* src = emb + (size_t)tok * En;
  int e = threadIdx.x * 4;
  float4 v = *(const float4*)(src + e);
  h16x4 o = { (h16)v.x, (h16)v.y, (h16)v.z, (h16)v.w };
  *(h16x4*)(Xh + (size_t)t * En + e) = o;
}

// ================= mega kernel: GI0 + gru dataflow + progressive head =================

__device__ __forceinline__ void wait_fL1(int* fL1, int target, int tid) {
  if (tid < 64) {
    for (;;) {
      int v = __hip_atomic_load(&fL1[tid << 5], __ATOMIC_RELAXED, __HIP_MEMORY_SCOPE_AGENT);
      if (__all(v >= target)) break;
      __builtin_amdgcn_s_sleep(8);
    }
  }
  __syncthreads();
  asm volatile("" ::: "memory");
}

__device__ __forceinline__ void wait_cnt(int* c, int target, int tid) {
  if (tid == 0) {
    while (__hip_atomic_load(c, __ATOMIC_RELAXED, __HIP_MEMORY_SCOPE_AGENT) < target)
      __builtin_amdgcn_s_sleep(8);
  }
  __syncthreads();
  asm volatile("" ::: "memory");
}

__device__ __forceinline__ void publish_cnt(int* c) {
  __syncthreads();                   // drains each wave's vmem before barrier
  if (threadIdx.x == 0) {
    __threadfence();                 // push block's stores to the coherence point
    atomicAdd(c, 1);
  }
}

// 128x128 GEMM, 384 threads (waves 4,5 stage-only). OUTF32: f32 C (ldc), else h16 C (ldc)
template<int OUTF32>
__device__ __forceinline__ void gemm_t128(
    const h16* __restrict__ A, const h16* __restrict__ B, const float* __restrict__ bias,
    void* __restrict__ C, int ldc, int K, int relu, char* dyn, int tid)
{
  h16* As = (h16*)dyn;
  h16* Bs = (h16*)(dyn + 16384);
  int l = tid & 63, wv = tid >> 6;
  int wr = wv >> 1, wc = wv & 1;
  f32x4 acc[4][4];
#pragma unroll
  for (int m = 0; m < 4; ++m)
#pragma unroll
    for (int n = 0; n < 4; ++n) acc[m][n] = (f32x4){0.f, 0.f, 0.f, 0.f};
  int nkt = K >> 6;
  for (int kt = 0; kt < nkt; ++kt) {
    const h16* Ag = A + kt * 64;
    const h16* Bg = B + kt * 64;
    for (int c = tid; c < 2048; c += 384) {
      int half = c >> 10, cc = c & 1023, row = cc >> 3, slot = cc & 7;
      const h16* src = (half ? Bg : Ag) + (size_t)row * K + slot * 8;
      uint4 v = *(const uint4*)src;
      h16* dst = (half ? Bs : As) + row * 64 + ((slot ^ (row & 7)) << 3);
      *(uint4*)dst = v;
    }
    __syncthreads();
    if (wv < 4) {
#pragma unroll
      for (int kk = 0; kk < 2; ++kk) {
        h16x8 af[4], bfr[4];
        int rb = wr * 64 + (l & 15);
        int cb2 = wc * 64 + (l & 15);
        int slot = kk * 4 + (l >> 4);
#pragma unroll
        for (int m = 0; m < 4; ++m) {
          int r = rb + m * 16;
          af[m] = *(const h16x8*)&As[r * 64 + ((slot ^ (r & 7)) << 3)];
        }
#pragma unroll
        for (int n = 0; n < 4; ++n) {
          int r = cb2 + n * 16;
          bfr[n] = *(const h16x8*)&Bs[r * 64 + ((slot ^ (r & 7)) << 3)];
        }
#pragma unroll
        for (int m = 0; m < 4; ++m)
#pragma unroll
          for (int n = 0; n < 4; ++n)
            acc[m][n] = __builtin_amdgcn_mfma_f32_16x16x32_f16(af[m], bfr[n], acc[m][n], 0, 0, 0);
      }
    }
    __syncthreads();
  }
  if (wv < 4) {
#pragma unroll
    for (int m = 0; m < 4; ++m) {
      int row0 = wr * 64 + m * 16 + ((l >> 4) << 2);
#pragma unroll
      for (int n = 0; n < 4; ++n) {
        int col = wc * 64 + n * 16 + (l & 15);
        float bv = bias[col];
#pragma unroll
        for (int i = 0; i < 4; ++i) {
          float v = acc[m][n][i] + bv;
          if (relu) v = fmaxf(v, 0.f);
          if (OUTF32) ((float*)C)[(size_t)(row0 + i) * ldc + col] = v;
          else        ((h16*)C)[(size_t)(row0 + i) * ldc + col] = (h16)v;
        }
      }
    }
  }
}

// 128x256 logit GEMM, 384 threads; writes f32 with (b*128+s) row remap
__device__ __forceinline__ void gemm_headlogit(
    const h16* __restrict__ A, const h16* __restrict__ B, const float* __restrict__ bias,
    float* __restrict__ C, int growbase, char* dyn, int tid)
{
  h16* As = (h16*)dyn;                 // 128*64
  h16* Bs = (h16*)(dyn + 16384);       // 256*64
  int l = tid & 63, wv = tid >> 6;
  int wr = wv >> 1, wc = wv & 1;
  f32x4 acc[4][8];
#pragma unroll
  for (int m = 0; m < 4; ++m)
#pragma unroll
    for (int n = 0; n < 8; ++n) acc[m][n] = (f32x4){0.f, 0.f, 0.f, 0.f};
  for (int kt = 0; kt < 8; ++kt) {
    const h16* Ag = A + kt * 64;
    const h16* Bg = B + kt * 64;
    for (int c = tid; c < 3072; c += 384) {
      int isB = (c >= 1024);
      int cc = isB ? (c - 1024) : c;
      int row = cc >> 3, slot = cc & 7;
      const h16* src = (isB ? Bg : Ag) + (size_t)row * 512 + slot * 8;
      uint4 v = *(const uint4*)src;
      h16* dst = (isB ? Bs : As) + row * 64 + ((slot ^ (row & 7)) << 3);
      *(uint4*)dst = v;
    }
    __syncthreads();
    if (wv < 4) {
#pragma unroll
      for (int kk = 0; kk < 2; ++kk) {
        h16x8 af[4], bfr[8];
        int rb = wr * 64 + (l & 15);
        int cb2 = wc * 128 + (l & 15);
        int slot = kk * 4 + (l >> 4);
#pragma unroll
        for (int m = 0; m < 4; ++m) {
          int r = rb + m * 16;
          af[m] = *(const h16x8*)&As[r * 64 + ((slot ^ (r & 7)) << 3)];
        }
#pragma unroll
        for (int n = 0; n < 8; ++n) {
          int r = cb2 + n * 16;
          bfr[n] = *(const h16x8*)&Bs[r * 64 + ((slot ^ (r & 7)) << 3)];
        }
#pragma unroll
        for (int m = 0; m < 4; ++m)
#pragma unroll
          for (int n = 0; n < 8; ++n)
            acc[m][n] = __builtin_amdgcn_mfma_f32_16x16x32_f16(af[m], bfr[n], acc[m][n], 0, 0, 0);
      }
    }
    __syncthreads();
  }
  if (wv < 4) {
#pragma unroll
    for (int m = 0; m < 4; ++m) {
      int row0 = wr * 64 + m * 16 + ((l >> 4) << 2);
#pragma unroll
      for (int n = 0; n < 8; ++n) {
        int col = wc * 128 + n * 16 + (l & 15);
        float bv = bias[col];
#pragma unroll
        for (int i = 0; i < 4; ++i) {
          int grow = growbase + row0 + i;
          int rr = ((grow & 15) << 7) + (grow >> 4);   // b*128 + s
          C[(size_t)rr * Vn + col] = acc[m][n][i] + bv;
        }
      }
    }
  }
}

__global__ __launch_bounds__(384) void mega(
    const float* __restrict__ gi0,       // produced in-kernel by GI0 blocks
    const float* __restrict__ hidden,
    const h16* __restrict__ hinit16,
    const float* __restrict__ whh0, const float* __restrict__ bhh0,
    const float* __restrict__ wih1, const float* __restrict__ bih1,
    const float* __restrict__ whh1, const float* __restrict__ bhh1,
    h16* __restrict__ h0ring, h16* __restrict__ H1A,
    int* __restrict__ flags,
    const h16* __restrict__ Xh, const h16* __restrict__ wih0H, const float* __restrict__ b_ih0,
    const h16* __restrict__ w1H, const float* __restrict__ b1, h16* __restrict__ Tb,
    const h16* __restrict__ w2H, const float* __restrict__ b2, h16* __restrict__ Ub,
    const h16* __restrict__ embH, const float* __restrict__ b_gen,
    float* __restrict__ out)
{
  extern __shared__ char dyn[];
  int bid = blockIdx.x;
  int tid = threadIdx.x;

  __threadfence();                   // replay-staleness guard (inv local caches)

  int* fL0   = flags;                // 32 flags @ stride 32 ints
  int* fL1   = flags + 1024;         // 64 flags @ stride 32 ints
  int* cnt1  = flags + 3072;         // 16 counters @ stride 8 ints
  int* cnt2  = flags + 3328;         // 16 counters @ stride 8 ints
  int* cntGI = flags + 3584;         // 16 counters @ stride 8 ints

  if (bid < NL0 + NL1) {
    // ---------------- gru dataflow (round-8 skeleton; f32 weights cvt in-register) ----------------
    float* exch = (float*)dyn;       // 5 x 256 floats
    int w = tid >> 6, l = tid & 63;
    int li = l & 15;
    int ko = (l >> 4) << 3;
    int b0 = (l >> 4) << 2;

    if (bid < NL0) {
      int gate = w >> 1, ch = w & 1;
      int j = bid * 32 + ch * 16 + li;
      h16x8 Bf[32];
      {
        const float* wp = whh0 + ((size_t)((gate << 10) + j) << 10) + ko;
#pragma unroll
        for (int t = 0; t < 32; ++t) {
          float4 u0 = *(const float4*)(wp + t * 32);
          float4 u1 = *(const float4*)(wp + t * 32 + 4);
          h16x8 f = { (h16)u0.x, (h16)u0.y, (h16)u0.z, (h16)u0.w,
                      (h16)u1.x, (h16)u1.y, (h16)u1.z, (h16)u1.w };
          Bf[t] = f;
        }
      }
      float bR = 0.f, bZ = 0.f, bN = 0.f;
      float hprev[4];
      if (gate == 2) {
        bR = bhh0[j]; bZ = bhh0[1024 + j]; bN = bhh0[2048 + j];
#pragma unroll
        for (int i = 0; i < 4; ++i) hprev[i] = hidden[((b0 + i) << 10) + j];
      }
      for (int s = 0; s < Sn; ++s) {
        if (w == 0) {
          if (l < NL0 && s > 0)
            while (__hip_atomic_load(&fL0[l << 5], __ATOMIC_RELAXED, __HIP_MEMORY_SCOPE_AGENT) < s) {}
          if (l == 32)
            while (__hip_atomic_load(&cntGI[(s >> 3) << 3], __ATOMIC_RELAXED, __HIP_MEMORY_SCOPE_AGENT) < 24) {}
        }
        __syncthreads();
        asm volatile("" ::: "memory");
        float gr[4], gz[4], gn[4];
        if (gate == 2) {             // gi load after the GI-ready barrier; hides under MFMA
          const float* gb = gi0 + ((size_t)s << 4) * H3;
#pragma unroll
          for (int i = 0; i < 4; ++i) {
            const float* g = gb + (size_t)(b0 + i) * H3 + j;
            gr[i] = g[0]; gz[i] = g[1024]; gn[i] = g[2048];
          }
        }
        const h16* hsrc = (s == 0) ? hinit16 : h0ring + (((size_t)(s - 1)) << 14);
        const h16* Ap = hsrc + (li << 10) + ko;
        f32x4 acc = (f32x4){0.f, 0.f, 0.f, 0.f};
#pragma unroll
        for (int t = 0; t < 32; ++t)
          acc = __builtin_amdgcn_mfma_f32_16x16x32_f16(*(const h16x8*)(Ap + t * 32), Bf[t], acc, 0, 0, 0);
        if (w < 4) {
#pragma unroll
          for (int i = 0; i < 4; ++i) exch[w * 256 + ((b0 + i) << 4) + li] = acc[i];
        }
        __syncthreads();
        if (gate == 2) {
#pragma unroll
          for (int i = 0; i < 4; ++i) {
            int e = ((b0 + i) << 4) + li;
            float r = 1.f / (1.f + expf(-(exch[ch * 256 + e] + bR + gr[i])));
            float z = 1.f / (1.f + expf(-(exch[(2 + ch) * 256 + e] + bZ + gz[i])));
            float n = tanhf(gn[i] + r * (acc[i] + bN));
            float o = (1.f - z) * n + z * hprev[i];
            hprev[i] = o;
            h16 hv = (h16)o; unsigned short us; __builtin_memcpy(&us, &hv, 2);
            __hip_atomic_store((unsigned short*)h0ring + (((size_t)s) << 14) + ((b0 + i) << 10) + j,
                               us, __ATOMIC_RELAXED, __HIP_MEMORY_SCOPE_AGENT);
          }
        }
        __syncthreads();
        if (tid == 0)
          __hip_atomic_store(&fL0[bid << 5], s + 1, __ATOMIC_RELAXED, __HIP_MEMORY_SCOPE_AGENT);
      }
    } else {
      int bl = bid - NL0;
      int j = (bl << 4) + li;
      int isHH = (w >= 3);
      int gate = isHH ? (w - 3) : w;
      h16x8 Bf[32];
      {
        const float* wsrc = isHH ? whh1 : wih1;
        const float* wp = wsrc + ((size_t)((gate << 10) + j) << 10) + ko;
#pragma unroll
        for (int t = 0; t < 32; ++t) {
          float4 u0 = *(const float4*)(wp + t * 32);
          float4 u1 = *(const float4*)(wp + t * 32 + 4);
          h16x8 f = { (h16)u0.x, (h16)u0.y, (h16)u0.z, (h16)u0.w,
                      (h16)u1.x, (h16)u1.y, (h16)u1.z, (h16)u1.w };
          Bf[t] = f;
        }
      }
      float bIR = 0.f, bIZ = 0.f, bIN = 0.f, bHR = 0.f, bHZ = 0.f, bHN = 0.f;
      float hprev[4];
      if (w == 5) {
        bIR = bih1[j]; bIZ = bih1[1024 + j]; bIN = bih1[2048 + j];
        bHR = bhh1[j]; bHZ = bhh1[1024 + j]; bHN = bhh1[2048 + j];
#pragma unroll
        for (int i = 0; i < 4; ++i) hprev[i] = hidden[16384 + ((b0 + i) << 10) + j];
      }
      for (int s = 1; s <= Sn; ++s) {
        if (w == 0) {
          if (l < NL0)
            while (__hip_atomic_load(&fL0[l << 5], __ATOMIC_RELAXED, __HIP_MEMORY_SCOPE_AGENT) < s) {}
        } else if (w == 1 && s >= 2) {
          while (__hip_atomic_load(&fL1[l << 5], __ATOMIC_RELAXED, __HIP_MEMORY_SCOPE_AGENT) < s) {}
        }
        __syncthreads();
        asm volatile("" ::: "memory");
        const h16* hsrc = isHH
            ? ((s == 1) ? hinit16 + 16384 : H1A + (((size_t)(s - 2)) << 14))
            : (h0ring + (((size_t)(s - 1)) << 14));
        const h16* Ap = hsrc + (li << 10) + ko;
        f32x4 acc = (f32x4){0.f, 0.f, 0.f, 0.f};
#pragma unroll
        for (int t = 0; t < 32; ++t)
          acc = __builtin_amdgcn_mfma_f32_16x16x32_f16(*(const h16x8*)(Ap + t * 32), Bf[t], acc, 0, 0, 0);
        if (w < 5) {
#pragma unroll
          for (int i = 0; i < 4; ++i) exch[w * 256 + ((b0 + i) << 4) + li] = acc[i];
        }
        __syncthreads();
        if (w == 5) {
#pragma unroll
          for (int i = 0; i < 4; ++i) {
            int e = ((b0 + i) << 4) + li;
            float r = 1.f / (1.f + expf(-(exch[e] + bIR + exch[768 + e] + bHR)));
            float z = 1.f / (1.f + expf(-(exch[256 + e] + bIZ + exch[1024 + e] + bHZ)));
            float n = tanhf(exch[512 + e] + bIN + r * (acc[i] + bHN));
            float o = (1.f - z) * n + z * hprev[i];
            hprev[i] = o;
            h16 hv = (h16)o; unsigned short us; __builtin_memcpy(&us, &hv, 2);
            __hip_atomic_store((unsigned short*)H1A + (((size_t)(s - 1)) << 14) + ((b0 + i) << 10) + j,
                               us, __ATOMIC_RELAXED, __HIP_MEMORY_SCOPE_AGENT);
          }
        }
        __syncthreads();
        if (tid == 0)
          __hip_atomic_store(&fL1[bl << 5], s + 1, __ATOMIC_RELAXED, __HIP_MEMORY_SCOPE_AGENT);
      }
    }
    return;
  }

  int hb = bid - (NL0 + NL1);

  if (hb < NGI) {
    // ---------------- GI0 producer: tile g = p*24 + n ----------------
    int p = hb / 24, n = hb % 24;
    gemm_t128<1>(Xh + (size_t)(p * 128) * En, wih0H + (size_t)(n * 128) * En,
                 b_ih0 + n * 128, (float*)gi0 + (size_t)(p * 128) * H3 + n * 128,
                 H3, En, 0, dyn, tid);
    publish_cnt(&cntGI[p << 3]);
    return;
  }

  // ---------------- progressive head: persistent col-blocks looping panels ----------------
  int hh = hb - NGI;
  if (hh < 8) {
    int r = hh;
    for (int m = 0; m < 16; ++m) {
      wait_fL1(fL1, 8 * m + 9, tid);
      gemm_t128<0>(H1A + (size_t)(m * 128) * Hn, w1H + (size_t)(r * 128) * Hn,
                   b1 + r * 128, Tb + (size_t)(m * 128) * Hn + r * 128, Hn, Hn, 1, dyn, tid);
      publish_cnt(&cnt1[m << 3]);
    }
  } else if (hh < 12) {
    int rn = hh - 8;
    for (int m = 0; m < 16; ++m) {
      wait_cnt(&cnt1[m << 3], 8, tid);
      gemm_t128<0>(Tb + (size_t)(m * 128) * Hn, w2H + (size_t)(rn * 128) * Hn,
                   b2 + rn * 128, Ub + (size_t)(m * 128) * En + rn * 128, En, Hn, 0, dyn, tid);
      publish_cnt(&cnt2[m << 3]);
    }
  } else {
    int np = hh - 12;                // 0..124
    for (int m = 0; m < 16; ++m) {
      wait_cnt(&cnt2[m << 3], 4, tid);
      gemm_headlogit(Ub + (size_t)(m * 128) * En, embH + (size_t)(np * 256) * En,
                     b_gen + np * 256, out + np * 256, m * 128, dyn, tid);
    }
  }
}

extern "C" void kernel_launch(void* const* d_in, const int* in_sizes, int n_in,
                              void* d_out, int out_size, void* d_ws, size_t ws_size,
                              hipStream_t stream) {
  const float* hidden = (const float*)d_in[0];
  const int*   trg    = (const int*)d_in[1];
  const float* emb    = (const float*)d_in[2];
  const float* w_ih0  = (const float*)d_in[3];
  const float* w_hh0  = (const float*)d_in[4];
  const float* b_ih0  = (const float*)d_in[5];
  const float* b_hh0  = (const float*)d_in[6];
  const float* w_ih1  = (const float*)d_in[7];
  const float* w_hh1  = (const float*)d_in[8];
  const float* b_ih1  = (const float*)d_in[9];
  const float* b_hh1  = (const float*)d_in[10];
  const float* w1     = (const float*)d_in[11];
  const float* b1     = (const float*)d_in[12];
  const float* w2     = (const float*)d_in[13];
  const float* b2     = (const float*)d_in[14];
  const float* b_gen  = (const float*)d_in[15];

  char* ws = (char*)d_ws;
  size_t off = 0;
  float* GI0    = (float*)(ws + off); off += (size_t)Sn * Bn * H3 * 4;      // 25.2 MB
  h16* Xh       = (h16*)(ws + off);   off += (size_t)Sn * Bn * En * 2;
  h16* embH     = (h16*)(ws + off);   off += (size_t)Vn * En * 2;
  h16* wih0H    = (h16*)(ws + off);   off += (size_t)H3 * En * 2;
  h16* w1H      = (h16*)(ws + off);   off += (size_t)Hn * Hn * 2;
  h16* w2H      = (h16*)(ws + off);   off += (size_t)En * Hn * 2;
  h16* H1A      = (h16*)(ws + off);   off += (size_t)Sn * Bn * Hn * 2;      // 4.2 MB
  h16* h0ring   = (h16*)(ws + off);   off += (size_t)Sn * Bn * Hn * 2;      // 4.2 MB
  h16* hinit16  = (h16*)(ws + off);   off += (size_t)2 * Bn * Hn * 2;
  h16* Tb       = (h16*)(ws + off);   off += (size_t)Sn * Bn * Hn * 2;      // 4.2 MB
  h16* Ub       = (h16*)(ws + off);   off += (size_t)Sn * Bn * En * 2;      // 2.1 MB
  int* flags    = (int*)(ws + off);   off += 16384;

  // converts (5 segments) + embedding gather
  cvt_all_k<<<19104, 256, 0, stream>>>(emb, w_ih0, w1, w2, hidden,
                                       embH, wih0H, w1H, w2H, hinit16);
  embed_k<<<Sn * Bn, 128, 0, stream>>>(trg, emb, Xh);

  // mega: 96 gru + 384 GI0 + 137 persistent head col-blocks, full dataflow sync
  (void)hipMemsetAsync(flags, 0, 16384, stream);
  const int LDSZ = 49152;
  (void)hipFuncSetAttribute(reinterpret_cast<const void*>(mega),
                            hipFuncAttributeMaxDynamicSharedMemorySize, LDSZ);
  mega<<<NL0 + NL1 + NGI + 137, 384, LDSZ, stream>>>(
      GI0, hidden, hinit16, w_hh0, b_hh0, w_ih1, b_ih1, w_hh1, b_hh1,
      h0ring, H1A, flags, Xh, wih0H, b_ih0, w1H, b1, Tb, w2H, b2, Ub,
      embH, b_gen, (float*)d_out);
}